// Round 7
// baseline (184.574 us; speedup 1.0000x reference)
//
#include <hip/hip_runtime.h>
#include <hip/hip_bf16.h>
#include <math.h>
#include <type_traits>

#define D_MODEL 1024
#define NHEADS  16
#define DK      64
#define SEQ     2048
#define BATCH   2
#define QTILE   256

typedef __attribute__((ext_vector_type(8)))  short  short8;
typedef __attribute__((ext_vector_type(8)))  unsigned short ushort8;
typedef __attribute__((ext_vector_type(4)))  float  floatx4;
typedef __attribute__((ext_vector_type(16))) float  floatx16;

template <int N> using IC = std::integral_constant<int, N>;

__device__ __forceinline__ unsigned short f2bf(float f) {      // RNE
    union { float f; unsigned int u; } v; v.f = f;
    unsigned int u = v.u;
    return (unsigned short)((u + 0x7FFFu + ((u >> 16) & 1u)) >> 16);
}
__device__ __forceinline__ float bf2f(unsigned short u) {
    union { unsigned int u; float f; } v; v.u = ((unsigned int)u) << 16;
    return v.f;
}
__device__ __forceinline__ unsigned int fau(float f) {
    union { float f; unsigned int u; } v; v.f = f; return v.u;
}

// async global->LDS, 16B per lane. LDS dest = wave-uniform base + lane*16.
__device__ __forceinline__ void gload_lds16(const unsigned short* g, unsigned short* l) {
    __builtin_amdgcn_global_load_lds((__attribute__((address_space(1))) const void*)g,
                                     (__attribute__((address_space(3))) void*)l,
                                     16, 0, 0);
}

// ---------------- fused fp32 -> bf16 pack of x, w_qkv, w_out ----------------
#define X8 ((BATCH * SEQ * D_MODEL) / 8)
#define W8 ((3 * D_MODEL * D_MODEL) / 8)
#define O8 ((D_MODEL * D_MODEL) / 8)
__global__ __launch_bounds__(256) void pack_all(const float* __restrict__ x,
                                                const float* __restrict__ wq,
                                                const float* __restrict__ wo,
                                                unsigned short* __restrict__ xb,
                                                unsigned short* __restrict__ wqb,
                                                unsigned short* __restrict__ wob) {
    const int t = blockIdx.x * blockDim.x + threadIdx.x;
    const float* src; unsigned short* dst; int idx;
    if (t < X8)           { src = x;  dst = xb;  idx = t; }
    else if (t < X8 + W8) { src = wq; dst = wqb; idx = t - X8; }
    else if (t < X8 + W8 + O8) { src = wo; dst = wob; idx = t - X8 - W8; }
    else return;
    const float4 a = ((const float4*)src)[2 * idx];
    const float4 b = ((const float4*)src)[2 * idx + 1];
    short8 o;
    o[0] = (short)f2bf(a.x); o[1] = (short)f2bf(a.y);
    o[2] = (short)f2bf(a.z); o[3] = (short)f2bf(a.w);
    o[4] = (short)f2bf(b.x); o[5] = (short)f2bf(b.y);
    o[6] = (short)f2bf(b.z); o[7] = (short)f2bf(b.w);
    ((short8*)dst)[idx] = o;
}

// ---------------- QKV GEMM: 256x256 tile, BK=64, 8-phase counted-vmcnt pipeline ----
// Phase factorization (kk, mh): 8 ds_read_b128 + 16 MFMA per phase, 32 reads/K-tile.
// Staging order per tile: B0,B1,A0,A1 (2 gload each). Waits traced:
//   P0 vmcnt(2) drains B0,B1,A0(t); P1 vmcnt(2) drains A1(t); P2 vmcnt(4) no-op;
//   P3 vmcnt(4) drains B0(t+1) (3 phases old). Never drains to 0.
// T2 swizzle both-sides; T5 setprio; T1 XCD-contiguous block swizzle.
#define QKV_M 4096
#define QKV_N 3072
#define QKV_K 1024
#define QKV_NT (QKV_K / 64)

__global__ __launch_bounds__(512, 2) void gemm_qkv_8ph(const unsigned short* __restrict__ A,
                                                        const unsigned short* __restrict__ B,
                                                        unsigned short* __restrict__ C) {
    __shared__ __align__(16) unsigned short As[2][256][64];   // 64 KB
    __shared__ __align__(16) unsigned short Bs[2][256][64];   // 64 KB

    const int tid  = threadIdx.x;
    const int w    = tid >> 6;        // wave 0..7
    const int lane = tid & 63;
    const int quad = lane >> 4;
    const int lcol = lane & 15;
    const int wr   = w >> 2;          // 0..1  (M half: 128 rows)
    const int wc   = w & 3;           // 0..3  (N quarter: 64 cols)

    // XCD-contiguous swizzle: 192 blocks = 8 XCDs x 24
    const int f  = blockIdx.x;
    const int wg = (f & 7) * 24 + (f >> 3);
    const int tn = (wg % (QKV_N / 256)) * 256;
    const int tm = (wg / (QKV_N / 256)) * 256;

    const int srow8 = lane >> 3;      // staging: row within 8-row block
    const int sj    = lane & 7;       // staging: 16B chunk within row

    // stage A-group mh (rows {mh*64..+64} u {128+mh*64..+64}) of K-tile kt into buf
    auto stageA = [&](int buf, int kt, int mh) {
#pragma unroll
        for (int c = 0; c < 2; ++c) {
            const int r0 = mh * 64 + c * 128 + w * 8;
            const int r  = r0 + srow8;
            gload_lds16(A + (size_t)(tm + r) * QKV_K + kt * 64 + ((sj ^ (r & 7)) * 8),
                        &As[buf][r0][0]);
        }
    };
    // stage B-group nh (rows {k*64 + nh*32 .. +32 : k=0..3}) of K-tile kt into buf
    auto stageB = [&](int buf, int kt, int nh) {
#pragma unroll
        for (int c = 0; c < 2; ++c) {
            const int rho0 = c * 64 + w * 8;
            const int r0   = (rho0 >> 5) * 64 + nh * 32 + (rho0 & 31);
            const int r    = r0 + srow8;
            gload_lds16(B + (size_t)(tn + r) * QKV_K + kt * 64 + ((sj ^ (r & 7)) * 8),
                        &Bs[buf][r0][0]);
        }
    };

    floatx4 acc[8][4];
#pragma unroll
    for (int i = 0; i < 8; ++i)
#pragma unroll
        for (int j = 0; j < 4; ++j) acc[i][j] = (floatx4){0.f, 0.f, 0.f, 0.f};

    // phase (kk, mh): A-half x all-B at k-slice kk; 8 ds_read_b128 + 16 MFMA
    auto do_phase = [&](int buf, auto vmc, auto kkc, auto mhc, auto stager) {
        constexpr int VM = decltype(vmc)::value;
        constexpr int kk = decltype(kkc)::value;
        constexpr int mh = decltype(mhc)::value;
        if constexpr (VM == 2) asm volatile("s_waitcnt vmcnt(2)" ::: "memory");
        else                   asm volatile("s_waitcnt vmcnt(4)" ::: "memory");
        __builtin_amdgcn_s_barrier();
        asm volatile("" ::: "memory");          // no LDS reads above the barrier
        short8 a[4], b[4];
#pragma unroll
        for (int i = 0; i < 4; ++i) {
            const int r = wr * 128 + mh * 64 + i * 16 + lcol;
            a[i] = *(const short8*)&As[buf][r][((kk * 4 + quad) ^ (r & 7)) * 8];
        }
#pragma unroll
        for (int j = 0; j < 4; ++j) {
            const int r = wc * 64 + j * 16 + lcol;
            b[j] = *(const short8*)&Bs[buf][r][((kk * 4 + quad) ^ (r & 7)) * 8];
        }
        stager();
        __builtin_amdgcn_s_setprio(1);
#pragma unroll
        for (int i = 0; i < 4; ++i)
#pragma unroll
            for (int j = 0; j < 4; ++j)
                acc[mh * 4 + i][j] = __builtin_amdgcn_mfma_f32_16x16x32_bf16(
                    a[i], b[j], acc[mh * 4 + i][j], 0, 0, 0);
        __builtin_amdgcn_s_setprio(0);
    };

    // prologue: tile 0 -> buf 0, staging order B0 B1 A0 A1
    stageB(0, 0, 0); stageB(0, 0, 1); stageA(0, 0, 0); stageA(0, 0, 1);

    for (int t = 0; t < QKV_NT; ++t) {
        const int buf = t & 1, nb = buf ^ 1;
        const int kn = (t + 1 == QKV_NT) ? 0 : t + 1;   // wrap: dead restage keeps invariant
        do_phase(buf, IC<2>{}, IC<0>{}, IC<0>{}, [&] { stageB(nb, kn, 0); });
        do_phase(buf, IC<2>{}, IC<0>{}, IC<1>{}, [&] { stageB(nb, kn, 1); });
        do_phase(buf, IC<4>{}, IC<1>{}, IC<0>{}, [&] { stageA(nb, kn, 0); });
        do_phase(buf, IC<4>{}, IC<1>{}, IC<1>{}, [&] { stageA(nb, kn, 1); });
    }

    // epilogue: C-write (bf16)
#pragma unroll
    for (int i = 0; i < 8; ++i) {
#pragma unroll
        for (int rr = 0; rr < 4; ++rr) {
            const int row = tm + wr * 128 + i * 16 + quad * 4 + rr;
#pragma unroll
            for (int jf = 0; jf < 4; ++jf) {
                const int col = tn + wc * 64 + jf * 16 + lcol;
                C[(size_t)row * QKV_N + col] = f2bf(acc[i][jf][rr]);
            }
        }
    }
}

// ---------------- out-proj GEMM: 128x128 tile, BK=64, 8-phase counted-vmcnt ----------
#define OUT_M 4096
#define OUT_N 1024
#define OUT_K 1024
#define OUT_NT (OUT_K / 64)

__global__ __launch_bounds__(512, 2) void gemm_out_8ph(const unsigned short* __restrict__ A,
                                                       const unsigned short* __restrict__ B,
                                                       const float* __restrict__ bias,
                                                       float* __restrict__ C) {
    __shared__ __align__(16) unsigned short As[2][128][64];   // 32 KB
    __shared__ __align__(16) unsigned short Bs[2][128][64];   // 32 KB

    const int tid  = threadIdx.x;
    const int w    = tid >> 6;        // wave 0..7
    const int lane = tid & 63;
    const int quad = lane >> 4;
    const int lcol = lane & 15;
    const int wr   = w >> 2;          // 0..1  (M half: 64 rows)
    const int wc   = w & 3;           // 0..3  (N quarter: 32 cols)

    // XCD-contiguous swizzle: 256 blocks = 8 XCDs x 32
    const int f  = blockIdx.x;
    const int wg = (f & 7) * 32 + (f >> 3);
    const int tn = (wg & 7) * 128;    // OUT_N/128 = 8
    const int tm = (wg >> 3) * 128;   // OUT_M/128 = 32

    const int srow8 = lane >> 3;
    const int sj    = lane & 7;

    // A-group mh: rows {mh*32+[0,32)} u {64+mh*32+[0,32)}; 8 waves x 8 rows, 1 gload
    auto stageA = [&](int buf, int kt, int mh) {
        const int r0 = (w & 3) * 8 + mh * 32 + (w >> 2) * 64;
        const int r  = r0 + srow8;
        gload_lds16(A + (size_t)(tm + r) * OUT_K + kt * 64 + ((sj ^ (r & 7)) * 8),
                    &As[buf][r0][0]);
    };
    // B-group nh: rows {c*32 + nh*16 + [0,16) : c=0..3}; 8 waves x 8 rows, 1 gload
    auto stageB = [&](int buf, int kt, int nh) {
        const int r0 = (w >> 1) * 32 + nh * 16 + (w & 1) * 8;
        const int r  = r0 + srow8;
        gload_lds16(B + (size_t)(tn + r) * OUT_K + kt * 64 + ((sj ^ (r & 7)) * 8),
                    &Bs[buf][r0][0]);
    };

    floatx4 acc[4][2];
#pragma unroll
    for (int i = 0; i < 4; ++i)
#pragma unroll
        for (int j = 0; j < 2; ++j) acc[i][j] = (floatx4){0.f, 0.f, 0.f, 0.f};

    auto do_phase = [&](int buf, auto vmc, auto kkc, auto mhc, auto stager) {
        constexpr int VM = decltype(vmc)::value;
        constexpr int kk = decltype(kkc)::value;
        constexpr int mh = decltype(mhc)::value;
        if constexpr (VM == 1) asm volatile("s_waitcnt vmcnt(1)" ::: "memory");
        else                   asm volatile("s_waitcnt vmcnt(2)" ::: "memory");
        __builtin_amdgcn_s_barrier();
        asm volatile("" ::: "memory");          // no LDS reads above the barrier
        short8 a[2], b[2];
#pragma unroll
        for (int i = 0; i < 2; ++i) {
            const int r = wr * 64 + mh * 32 + i * 16 + lcol;
            a[i] = *(const short8*)&As[buf][r][((kk * 4 + quad) ^ (r & 7)) * 8];
        }
#pragma unroll
        for (int j = 0; j < 2; ++j) {
            const int r = wc * 32 + j * 16 + lcol;
            b[j] = *(const short8*)&Bs[buf][r][((kk * 4 + quad) ^ (r & 7)) * 8];
        }
        stager();
        __builtin_amdgcn_s_setprio(1);
#pragma unroll
        for (int i = 0; i < 2; ++i)
#pragma unroll
            for (int j = 0; j < 2; ++j)
                acc[mh * 2 + i][j] = __builtin_amdgcn_mfma_f32_16x16x32_bf16(
                    a[i], b[j], acc[mh * 2 + i][j], 0, 0, 0);
        __builtin_amdgcn_s_setprio(0);
    };

    // prologue: tile 0 -> buf 0, order B0 B1 A0 A1
    stageB(0, 0, 0); stageB(0, 0, 1); stageA(0, 0, 0); stageA(0, 0, 1);

    for (int t = 0; t < OUT_NT; ++t) {
        const int buf = t & 1, nb = buf ^ 1;
        const int kn = (t + 1 == OUT_NT) ? 0 : t + 1;   // wrap: dead restage keeps invariant
        do_phase(buf, IC<1>{}, IC<0>{}, IC<0>{}, [&] { stageB(nb, kn, 0); });
        do_phase(buf, IC<1>{}, IC<0>{}, IC<1>{}, [&] { stageB(nb, kn, 1); });
        do_phase(buf, IC<2>{}, IC<1>{}, IC<0>{}, [&] { stageA(nb, kn, 0); });
        do_phase(buf, IC<2>{}, IC<1>{}, IC<1>{}, [&] { stageA(nb, kn, 1); });
    }

    // epilogue: fp32 C-write + bias
#pragma unroll
    for (int i = 0; i < 4; ++i) {
#pragma unroll
        for (int rr = 0; rr < 4; ++rr) {
            const int row = tm + wr * 64 + i * 16 + quad * 4 + rr;
#pragma unroll
            for (int j = 0; j < 2; ++j) {
                const int col = tn + wc * 32 + j * 16 + lcol;
                C[(size_t)row * OUT_N + col] = acc[i][j][rr] + bias[col];
            }
        }
    }
}

// ---------------- fused RoPE pack (Q*0.125*log2e, K) + sigma-permuted V transpose ---
// Key u within each 64-tile is stored at column c(u) = (u&48) | (8*((u>>2)&1) + (u&3)
// + 4*((u>>3)&1)) so PV's A-operand (= S^T C-regs) and B-operand (V) agree on the
// 32x32x16 MFMA k-index mapping.
__global__ __launch_bounds__(256) void rope_vtrans(const unsigned short* __restrict__ qkvb,
                                                   unsigned short* __restrict__ Qb,
                                                   unsigned short* __restrict__ Kb,
                                                   unsigned short* __restrict__ Vtg) {
    const int st = blockIdx.x, h = blockIdx.y, b = blockIdx.z;
    const int tid = threadIdx.x;
    const int s0 = st * 64;

    // ---- RoPE on Q,K ----
    const int i  = tid & 31;
    const int r0 = tid >> 5;                   // 0..7
    const float inv_freq = exp2f(-(2.0f * (float)i / (float)DK) * log2f(50.0f));
    const float QSCALE = 0.125f * 1.44269504f; // 1/sqrt(dk) * log2(e)
#pragma unroll
    for (int pass = 0; pass < 8; ++pass) {
        const int s = s0 + r0 + pass * 8;
        const size_t in_base = ((size_t)(b * SEQ + s)) * (3 * D_MODEL) + h * DK + 2 * i;
        const float q0 = bf2f(qkvb[in_base]),           q1 = bf2f(qkvb[in_base + 1]);
        const float k0 = bf2f(qkvb[in_base + D_MODEL]), k1 = bf2f(qkvb[in_base + D_MODEL + 1]);
        float sn, cs;
        __sincosf((float)s * inv_freq, &sn, &cs);
        const size_t ob = (((size_t)(b * NHEADS + h)) * SEQ + s) * DK + 2 * i;
        const unsigned int qw = (unsigned int)f2bf((q0 * cs - q1 * sn) * QSCALE)
                              | ((unsigned int)f2bf((q1 * cs + q0 * sn) * QSCALE) << 16);
        const unsigned int kw = (unsigned int)f2bf(k0 * cs - k1 * sn)
                              | ((unsigned int)f2bf(k1 * cs + k0 * sn) << 16);
        *(unsigned int*)&Qb[ob] = qw;
        *(unsigned int*)&Kb[ob] = kw;
    }

    // ---- V transpose with sigma column permutation ----
    __shared__ unsigned short Lt[64][65];
    const int r = tid >> 3;                    // 0..31 (key within tile)
    const int c = (tid & 7) * 8;
    const size_t in_row = ((size_t)(b * SEQ + s0 + r)) * (3 * D_MODEL) + 2 * D_MODEL + h * DK + c;
    const ushort8 v0 = *(const ushort8*)&qkvb[in_row];
    const ushort8 v1 = *(const ushort8*)&qkvb[in_row + (size_t)32 * (3 * D_MODEL)];
    const int u0 = r, u1 = r + 32;
    const int kc0 = (u0 & 48) | (8 * ((u0 >> 2) & 1) + (u0 & 3) + 4 * ((u0 >> 3) & 1));
    const int kc1 = (u1 & 48) | (8 * ((u1 >> 2) & 1) + (u1 & 3) + 4 * ((u1 >> 3) & 1));
#pragma unroll
    for (int j = 0; j < 8; ++j) Lt[c + j][kc0] = v0[j];
#pragma unroll
    for (int j = 0; j < 8; ++j) Lt[c + j][kc1] = v1[j];
    __syncthreads();
    const size_t bh = (size_t)(b * NHEADS + h);
    ushort8 o0, o1;
#pragma unroll
    for (int j = 0; j < 8; ++j) { o0[j] = Lt[r][c + j]; o1[j] = Lt[r + 32][c + j]; }
    unsigned short* orow = Vtg + (bh * DK + r) * SEQ + s0 + c;   // r = d-row
    *(ushort8*)orow = o0;
    *(ushort8*)(orow + (size_t)32 * SEQ) = o1;
}

// ---------------- flash attention: QTILE=256, 8 waves = 4 q-quarters x 2 key-halves -
// LDS-read-reuse shape: wave (wq = w&3, kh = w>>2) owns 64 q rows x the kh key-half
// (32 keys) of every 64-key tile. Each kf/vf ds_read_b128 feeds TWO MFMAs (both
// q-subtiles) -> 8 reads per 16 MFMAs/wave/tile, HALF the per-CU LDS read traffic of
// the 32qx64k shape (which was the measured common limiter of r3/r6 at ~44-45 us).
// K-striped partial O/l -> kh-pair reduction epilogue via 2-round LDS overlay.
#define LDW 72

__global__ __launch_bounds__(512, 2) void flash_attn(const unsigned short* __restrict__ Qb,
                                                     const unsigned short* __restrict__ Kb,
                                                     const unsigned short* __restrict__ Vtg,
                                                     unsigned short* __restrict__ attnb) {
    const int tid  = threadIdx.x;
    const int wv   = tid >> 6;                // wave 0..7
    const int lane = tid & 63;
    const int l31  = lane & 31;
    const int lh   = lane >> 5;               // lane half (k-subgroup)
    const int wq   = wv & 3;                  // q-quarter (64 rows)
    const int kh   = wv >> 2;                 // key-half of each 64-tile
    const int kb   = kh * 32;

    // XCD-grouping swizzle: 256 blocks = 8 XCDs x 32; consecutive w share (b,h) -> K/V
    // (512 KB/bh) L2-resident per XCD.
    const int f  = blockIdx.x + gridDim.x * (blockIdx.y + gridDim.y * blockIdx.z);
    const int w  = (f & 7) * 32 + (f >> 3);   // bijective (256 % 8 == 0)
    const int qt = w & 7;                     // 0..7 (tiles of 256 queries)
    const int h  = (w >> 3) & 15;
    const int b  = w >> 7;

    __shared__ __align__(16) unsigned char smem[36864];          // 2 x (Ks 9216 + Vt 9216)
    unsigned short (*Ks0)[LDW] = (unsigned short (*)[LDW])(smem);
    unsigned short (*Vt0)[LDW] = (unsigned short (*)[LDW])(smem +  9216);
    unsigned short (*Ks1)[LDW] = (unsigned short (*)[LDW])(smem + 18432);
    unsigned short (*Vt1)[LDW] = (unsigned short (*)[LDW])(smem + 27648);
    // epilogue overlays (staging dead): Osh [128][68] f32 = 34816 B + lsh 256 f32 = 1 KB
    float* Osh = (float*)smem;
    float* lsh = (float*)(smem + 34816);

    const size_t bh = (size_t)(b * NHEADS + h);
    const unsigned short* Qg = Qb + (bh * SEQ + (size_t)qt * QTILE) * DK;
    const unsigned short* Kg = Kb + bh * SEQ * DK;
    const unsigned short* Vg = Vtg + bh * (size_t)DK * SEQ;

    // Q as B-operand for both q-subtiles of this wave's 64 rows
    short8 qfA[4], qfB[4];
#pragma unroll
    for (int t = 0; t < 4; ++t) {
        qfA[t] = *(const short8*)&Qg[(size_t)(wq * 64 + l31) * DK + t * 16 + lh * 8];
        qfB[t] = *(const short8*)&Qg[(size_t)(wq * 64 + 32 + l31) * DK + t * 16 + lh * 8];
    }

    // staging: 512 threads, each 1 short8 into Ks and 1 into Vt (64 rows x 64 cols)
    const int strow = tid >> 3;               // 0..63
    const int stcol = (tid & 7) * 8;
    const unsigned short* kg = &Kg[(size_t)strow * DK + stcol];
    const unsigned short* vg = &Vg[(size_t)strow * SEQ + stcol];

    short8 kr = *(const short8*)&kg[0];
    short8 vr = *(const short8*)&vg[0];

    floatx16 oaccA[2], oaccB[2];
    oaccA[0] = (floatx16)(0.f); oaccA[1] = (floatx16)(0.f);
    oaccB[0] = (floatx16)(0.f); oaccB[1] = (floatx16)(0.f);
    float lpA = 0.f, lpB = 0.f;               // l partials: q = wq*64 + {0,32} + l31

    // diag: key kt+kb+key_loc == q  <=>  kt = qt*256 + wq*64 + qs*32 - kb.
    // Only one of dktA/dktB is =0 mod 64 per wave (each diag element masked once).
    const int dktA = qt * QTILE + wq * 64 - kb;
    const int dktB = dktA + 32;

    auto compute = [&](unsigned short (*Ks)[LDW], unsigned short (*Vt)[LDW], int kt) {
        // ---- S^T = K Q^T : rows = this wave's 32-key half, cols = q (2 subtiles) ----
        floatx16 scA = (floatx16)(0.f), scB = (floatx16)(0.f);
        __builtin_amdgcn_s_setprio(1);
#pragma unroll
        for (int t = 0; t < 4; ++t) {
            const short8 kf = *(short8*)&Ks[kb + l31][t * 16 + lh * 8];   // shared by A,B
            scA = __builtin_amdgcn_mfma_f32_32x32x16_bf16(kf, qfA[t], scA, 0, 0, 0);
            scB = __builtin_amdgcn_mfma_f32_32x32x16_bf16(kf, qfB[t], scB, 0, 0, 0);
        }
        __builtin_amdgcn_s_setprio(0);

        // ---- diagonal mask ----
        if (kt == dktA) {
#pragma unroll
            for (int r = 0; r < 16; ++r) {
                const int key_loc = (r & 3) + 8 * (r >> 2) + 4 * lh;
                if (key_loc == l31) scA[r] = -1e30f;
            }
        }
        if (kt == dktB) {
#pragma unroll
            for (int r = 0; r < 16; ++r) {
                const int key_loc = (r & 3) + 8 * (r >> 2) + 4 * lh;
                if (key_loc == l31) scB[r] = -1e30f;
            }
        }

        // ---- P = exp2(S^T): native v_exp_f32 + v_perm trunc pack; lp accumulates ----
        short8 pA0, pA1, pB0, pB1;
        {
            union { unsigned int u[4]; short8 s8; } a0, a1, b0, b1;
#pragma unroll
            for (int d = 0; d < 4; ++d) {
                const float eA0 = __builtin_amdgcn_exp2f(scA[2 * d]);
                const float eA1 = __builtin_amdgcn_exp2f(scA[2 * d + 1]);
                a0.u[d] = __builtin_amdgcn_perm(fau(eA1), fau(eA0), 0x07060302u);
                const float eA2 = __builtin_amdgcn_exp2f(scA[8 + 2 * d]);
                const float eA3 = __builtin_amdgcn_exp2f(scA[8 + 2 * d + 1]);
                a1.u[d] = __builtin_amdgcn_perm(fau(eA3), fau(eA2), 0x07060302u);
                lpA += (eA0 + eA1) + (eA2 + eA3);
                const float eB0 = __builtin_amdgcn_exp2f(scB[2 * d]);
                const float eB1 = __builtin_amdgcn_exp2f(scB[2 * d + 1]);
                b0.u[d] = __builtin_amdgcn_perm(fau(eB1), fau(eB0), 0x07060302u);
                const float eB2 = __builtin_amdgcn_exp2f(scB[8 + 2 * d]);
                const float eB3 = __builtin_amdgcn_exp2f(scB[8 + 2 * d + 1]);
                b1.u[d] = __builtin_amdgcn_perm(fau(eB3), fau(eB2), 0x07060302u);
                lpB += (eB0 + eB1) + (eB2 + eB3);
            }
            pA0 = a0.s8; pA1 = a1.s8; pB0 = b0.s8; pB1 = b1.s8;
        }

        // ---- O += P V over this wave's key-half; each vf feeds 2 MFMAs ----
        __builtin_amdgcn_s_setprio(1);
#pragma unroll
        for (int nd = 0; nd < 2; ++nd) {
            const short8 vf0 = *(short8*)&Vt[nd * 32 + l31][kb + lh * 8];        // keys +0..15
            oaccA[nd] = __builtin_amdgcn_mfma_f32_32x32x16_bf16(pA0, vf0, oaccA[nd], 0, 0, 0);
            oaccB[nd] = __builtin_amdgcn_mfma_f32_32x32x16_bf16(pB0, vf0, oaccB[nd], 0, 0, 0);
            const short8 vf1 = *(short8*)&Vt[nd * 32 + l31][kb + 16 + lh * 8];   // keys +16..31
            oaccA[nd] = __builtin_amdgcn_mfma_f32_32x32x16_bf16(pA1, vf1, oaccA[nd], 0, 0, 0);
            oaccB[nd] = __builtin_amdgcn_mfma_f32_32x32x16_bf16(pB1, vf1, oaccB[nd], 0, 0, 0);
        }
        __builtin_amdgcn_s_setprio(0);
    };

    for (int kt = 0; kt < SEQ; kt += 128) {
        // ---- phase A: buffer 0, keys [kt, kt+64) ----
        *(short8*)&Ks0[strow][stcol] = kr;
        *(short8*)&Vt0[strow][stcol] = vr;
        __syncthreads();
        kr = *(const short8*)&kg[(size_t)(kt + 64) * DK];
        vr = *(const short8*)&vg[kt + 64];
        compute(Ks0, Vt0, kt);

        // ---- phase B: buffer 1, keys [kt+64, kt+128) ----
        *(short8*)&Ks1[strow][stcol] = kr;
        *(short8*)&Vt1[strow][stcol] = vr;
        __syncthreads();
        const int ktn = (kt + 128 < SEQ) ? kt + 128 : 0;
        kr = *(const short8*)&kg[(size_t)ktn * DK];
        vr = *(const short8*)&vg[ktn];
        compute(Ks1, Vt1, kt + 64);
    }

    // ---- epilogue: combine lane-halves, then kh-pair reduction via LDS (2 rounds) ----
    const float ltA = lpA + __shfl_xor(lpA, 32, 64);
    const float ltB = lpB + __shfl_xor(lpB, 32, 64);

    __syncthreads();                          // staging buffers dead
    if (kh == 1 && lh == 0) {                 // publish partner l
        lsh[wq * 64 + l31]      = ltA;
        lsh[wq * 64 + 32 + l31] = ltB;
    }
    unsigned short* obase = attnb + ((size_t)b * SEQ + (size_t)qt * QTILE + wq * 64) * D_MODEL
                          + h * DK;
    for (int round = 0; round < 2; ++round) {
        __syncthreads();
        if (kh == 1 && (wq & 1) == round) {   // writers: waves {4,6} then {5,7}
            const int base = (wq >> 1) * 64;
#pragma unroll
            for (int r = 0; r < 16; ++r) {
                const int mq = (r & 3) + 8 * (r >> 2) + 4 * lh;
                Osh[(base + mq) * 68 + l31]           = oaccA[0][r];
                Osh[(base + mq) * 68 + 32 + l31]      = oaccA[1][r];
                Osh[(base + 32 + mq) * 68 + l31]      = oaccB[0][r];
                Osh[(base + 32 + mq) * 68 + 32 + l31] = oaccB[1][r];
            }
        }
        __syncthreads();
        if (kh == 0 && (wq & 1) == round) {   // readers: waves {0,2} then {1,3}
            const int base = (wq >> 1) * 64;
            // 1.001953125 = 1/(1 - 2^-9): compensates mean truncation bias of bf16 P
            // (numerator uses trunc(P), denominator uses full-precision sums).
#pragma unroll
            for (int r = 0; r < 16; ++r) {
                const int mq = (r & 3) + 8 * (r >> 2) + 4 * lh;
                const float invA = 1.001953125f / (__shfl(ltA, mq, 64) + lsh[wq * 64 + mq]);
                const float invB = 1.001953125f / (__shfl(ltB, mq, 64) + lsh[wq * 64 + 32 + mq]);
                const float vA0 = (oaccA[0][r] + Osh[(base + mq) * 68 + l31]) * invA;
                const float vA1 = (oaccA[1][r] + Osh[(base + mq) * 68 + 32 + l31]) * invA;
                const float vB0 = (oaccB[0][r] + Osh[(base + 32 + mq) * 68 + l31]) * invB;
                const float vB1 = (oaccB[1][r] + Osh[(base + 32 + mq) * 68 + 32 + l31]) * invB;
                obase[(size_t)mq * D_MODEL + l31]             = f2bf(vA0);
                obase[(size_t)mq * D_MODEL + 32 + l31]        = f2bf(vA1);
                obase[(size_t)(32 + mq) * D_MODEL + l31]      = f2bf(vB0);
                obase[(size_t)(32 + mq) * D_MODEL + 32 + l31] = f2bf(vB1);
            }
        }
    }
}

extern "C" void kernel_launch(void* const* d_in, const int* in_sizes, int n_in,
                              void* d_out, int out_size, void* d_ws, size_t ws_size,
                              hipStream_t stream) {
    const float* x     = (const float*)d_in[0];
    const float* w_qkv = (const float*)d_in[1];
    const float* w_out = (const float*)d_in[2];
    const float* b_out = (const float*)d_in[3];
    float* out = (float*)d_out;

    const int M = BATCH * SEQ;                                   // 4096
    const size_t X_ELEMS    = (size_t)M * D_MODEL;
    const size_t WQKV_ELEMS = (size_t)3 * D_MODEL * D_MODEL;
    const size_t WOUT_ELEMS = (size_t)D_MODEL * D_MODEL;
    const size_t QKV_ELEMS  = (size_t)M * 3 * D_MODEL;
    const size_t HEAD_ELEMS = (size_t)BATCH * NHEADS * SEQ * DK;

    unsigned short* xb    = (unsigned short*)d_ws;
    unsigned short* wqkvb = xb + X_ELEMS;
    unsigned short* woutb = wqkvb + WQKV_ELEMS;
    unsigned short* qkvb  = woutb + WOUT_ELEMS;
    unsigned short* Qb    = qkvb + QKV_ELEMS;
    unsigned short* Kb    = Qb + HEAD_ELEMS;
    unsigned short* Vtg   = Kb + HEAD_ELEMS;                     // [B,H,64,S] sigma-permuted
    unsigned short* attnb = Vtg + HEAD_ELEMS;

    // 0) pack all inputs to bf16
    pack_all<<<(X8 + W8 + O8 + 255) / 256, 256, 0, stream>>>(x, w_qkv, w_out, xb, wqkvb, woutb);

    // 1) qkvb = xb @ wqkvb^T  (256^2 8-phase pipeline, (kk,mh) phases)
    gemm_qkv_8ph<<<(QKV_M / 256) * (QKV_N / 256), 512, 0, stream>>>(xb, wqkvb, qkvb);

    // 2) RoPE pack + sigma-permuted V transpose
    {
        dim3 grid(SEQ / 64, NHEADS, BATCH);
        rope_vtrans<<<grid, 256, 0, stream>>>(qkvb, Qb, Kb, Vtg);
    }
    // 3) flash attention (QTILE=256, 64q x 32k waves, LDS-read-reuse shape)
    {
        dim3 grid(SEQ / QTILE, NHEADS, BATCH);
        flash_attn<<<grid, 512, 0, stream>>>(Qb, Kb, Vtg, attnb);
    }
    // 4) out = attnb @ woutb^T + b_out  (128^2 8-phase pipeline, 256 blocks)
    gemm_out_8ph<<<(OUT_M / 128) * (OUT_N / 128), 512, 0, stream>>>(attnb, woutb, b_out, out);
}